// Round 3
// baseline (109.744 us; speedup 1.0000x reference)
//
#include <hip/hip_runtime.h>

// ---------------------------------------------------------------------------
// Complex Daubechies wavelet pyramid, 6 levels, circular boundary, 6 taps.
// d_out = [B, C, 2, H, W] fp32. Levels 0-2: one tiled kernel each (fused
// column pass -> row pass, LL band -> ws only). Levels 3-5: ONE kernel,
// one block per (B,C) plane, levels chained with __syncthreads (planes are
// independent -> no grid sync needed).
// Filters: LO palindromic, HI antipalindromic -> fold 6 taps to 3.
// Stage-2 output stride YW = 2TB+8 (16B-aligned windows) so stage 3 reads
// its 8-float tap window as 2x ds_read_b128 per array.
// ---------------------------------------------------------------------------

#define SQ2 0.7071067811865476

constexpr float kLOR0 = (float)(-0.0662912607 * SQ2);
constexpr float kLOR1 = (float)( 0.1104854346 * SQ2);
constexpr float kLOR2 = (float)( 0.6629126074 * SQ2);
constexpr float kLOI0 = (float)(-0.0855816496 * SQ2);
constexpr float kLOI1 = (float)(-0.0855816496 * SQ2);
constexpr float kLOI2 = (float)( 0.1711632992 * SQ2);
constexpr float kHIR0 = (float)(-0.0662912607 * SQ2);
constexpr float kHIR1 = (float)(-0.1104854346 * SQ2);
constexpr float kHIR2 = (float)( 0.6629126074 * SQ2);
constexpr float kHII0 = (float)( 0.0855816496 * SQ2);
constexpr float kHII1 = (float)(-0.0855816496 * SQ2);
constexpr float kHII2 = (float)(-0.1711632992 * SQ2);

typedef float f2v __attribute__((ext_vector_type(2)));

// 6-tap complex filter pair via (anti)symmetry. xr/xi: 6 consecutive values
// (register arrays, statically indexed after unroll).
__device__ __forceinline__ void band6(const float* xr, const float* xi,
                                      float& plr, float& pli, float& phr,
                                      float& phi) {
  const float s0 = xr[0] + xr[5], s1 = xr[1] + xr[4], s2 = xr[2] + xr[3];
  const float d0 = xr[0] - xr[5], d1 = xr[1] - xr[4], d2 = xr[2] - xr[3];
  const float t0 = xi[0] + xi[5], t1 = xi[1] + xi[4], t2 = xi[2] + xi[3];
  const float e0 = xi[0] - xi[5], e1 = xi[1] - xi[4], e2 = xi[2] - xi[3];
  plr = (kLOR0 * s0 + kLOR1 * s1 + kLOR2 * s2) -
        (kLOI0 * t0 + kLOI1 * t1 + kLOI2 * t2);
  pli = (kLOI0 * s0 + kLOI1 * s1 + kLOI2 * s2) +
        (kLOR0 * t0 + kLOR1 * t1 + kLOR2 * t2);
  phr = (kHIR0 * d0 + kHIR1 * d1 + kHIR2 * d2) -
        (kHII0 * e0 + kHII1 * e1 + kHII2 * e2);
  phi = (kHII0 * d0 + kHII1 * d1 + kHII2 * d2) +
        (kHIR0 * e0 + kHIR1 * e1 + kHIR2 * e2);
}

__device__ __forceinline__ void gload16(const float4* src, float4* ldsDst) {
  __builtin_amdgcn_global_load_lds(
      (__attribute__((address_space(1))) const void*)src,
      (__attribute__((address_space(3))) void*)ldsDst, 16, 0, 0);
}

// ---------------------------- main tiled kernel ----------------------------
template <int TB, bool HAS_IMAG, bool LL_TO_WS>
__global__ __launch_bounds__(256) void dwt_kernel(
    const float* __restrict__ inR, const float* __restrict__ inI,
    float* __restrict__ out, float* __restrict__ llR, float* __restrict__ llI,
    int h, int w, int tilesPerRow, int tilesPerPlane, int cpx8, int HW,
    int W0) {
  constexpr int RROWS = 2 * TB + 4;
  constexpr int F4PR = TB / 2 + 2;
  constexpr int SW = 4 * F4PR;
  constexpr int NF4 = RROWS * F4PR;
  constexpr int NF4P = ((NF4 + 255) / 256) * 256;
  constexpr int YW = 2 * TB + 8;   // mult of 4 -> 16B-aligned windows
  constexpr int C2 = 2 * TB + 4;   // stage-2 outputs per row
  constexpr int HB = TB / 2;
  constexpr int NJQ = TB / 2;

  __shared__ float4 s4R[NF4P];
  __shared__ float4 s4I[HAS_IMAG ? NF4P : 1];
  __shared__ __align__(16) float yLR[HB * YW], yLI[HB * YW];
  __shared__ __align__(16) float yHR[HB * YW], yHI[HB * YW];

  const int tid = threadIdx.x;
  int bid = (int)blockIdx.x;
  bid = (bid & 7) * cpx8 + (bid >> 3);  // XCD-contiguous chunks
  const int plane = bid / tilesPerPlane;
  const int trem = bid - plane * tilesPerPlane;
  const int ti = trem / tilesPerRow;
  const int tj = trem - ti * tilesPerRow;

  const int hm = h - 1;
  const int w4 = w >> 2, w4m = w4 - 1;
  const int rowstart = 2 * TB * ti - 3;
  const int col4start = HB * tj - 1;

  const float* pinR = inR + (size_t)plane * h * w;
  const float* pinI = HAS_IMAG ? (inI + (size_t)plane * h * w) : nullptr;

  // ---- stage 1: global -> LDS, width-16 async, linear LDS layout ----
  {
    const int lane = tid & 63;
    const int wid = tid >> 6;
    for (int c0 = wid * 64; c0 < NF4P; c0 += 256) {
      const int idx = c0 + lane;
      const int r = idx / F4PR;
      const int q = idx - r * F4PR;
      const int gr = (rowstart + r) & hm;
      const int gq = (col4start + q) & w4m;
      const size_t goff = (size_t)gr * w4 + gq;
      gload16((const float4*)pinR + goff, &s4R[c0]);
      if (HAS_IMAG) gload16((const float4*)pinI + goff, &s4I[c0]);
    }
  }
  __syncthreads();

  const float* sRf = (const float*)s4R;
  const float* sIf = (const float*)s4I;
  const int i0 = TB * ti, j0g = TB * tj;
  const int h2 = h >> 1, w2 = w >> 1;
  float* outR = out + (size_t)plane * 2 * HW;
  float* outI = outR + HW;

#pragma unroll
  for (int p = 0; p < 2; ++p) {
    // ---- stage 2: column pass; y[c] ~ padded col (c+1) ----
    for (int idx = tid; idx < HB * C2; idx += 256) {
      const int il = idx / C2;
      const int c = idx - il * C2;
      const int rb = 2 * (p * HB + il);
      const float* col = sRf + rb * SW + c + 1;
      const float x0 = col[0], x1 = col[SW], x2 = col[2 * SW];
      const float x3 = col[3 * SW], x4 = col[4 * SW], x5 = col[5 * SW];
      const float sr0 = x0 + x5, sr1 = x1 + x4, sr2 = x2 + x3;
      const float dr0 = x0 - x5, dr1 = x1 - x4, dr2 = x2 - x3;
      float lr = kLOR0 * sr0 + kLOR1 * sr1 + kLOR2 * sr2;
      float li = kLOI0 * sr0 + kLOI1 * sr1 + kLOI2 * sr2;
      float hr = kHIR0 * dr0 + kHIR1 * dr1 + kHIR2 * dr2;
      float hi = kHII0 * dr0 + kHII1 * dr1 + kHII2 * dr2;
      if (HAS_IMAG) {
        const float* colI = sIf + rb * SW + c + 1;
        const float z0 = colI[0], z1 = colI[SW], z2 = colI[2 * SW];
        const float z3 = colI[3 * SW], z4 = colI[4 * SW], z5 = colI[5 * SW];
        const float si0 = z0 + z5, si1 = z1 + z4, si2 = z2 + z3;
        const float di0 = z0 - z5, di1 = z1 - z4, di2 = z2 - z3;
        lr -= kLOI0 * si0 + kLOI1 * si1 + kLOI2 * si2;
        li += kLOR0 * si0 + kLOR1 * si1 + kLOR2 * si2;
        hr -= kHII0 * di0 + kHII1 * di1 + kHII2 * di2;
        hi += kHIR0 * di0 + kHIR1 * di1 + kHIR2 * di2;
      }
      const int yi = il * YW + c;
      yLR[yi] = lr;
      yLI[yi] = li;
      yHR[yi] = hr;
      yHI[yi] = hi;
    }
    __syncthreads();

    // ---- stage 3: row pass, 2 cols/thread, b128 window reads ----
    const int jq = tid & (NJQ - 1);
    const int il = tid / NJQ;
    if (il < HB) {
      const int base = il * YW + 4 * jq;
      float xLR[8], xLI[8], xHR[8], xHI[8];
      *(float4*)&xLR[0] = *(const float4*)&yLR[base];
      *(float4*)&xLR[4] = *(const float4*)&yLR[base + 4];
      *(float4*)&xLI[0] = *(const float4*)&yLI[base];
      *(float4*)&xLI[4] = *(const float4*)&yLI[base + 4];
      *(float4*)&xHR[0] = *(const float4*)&yHR[base];
      *(float4*)&xHR[4] = *(const float4*)&yHR[base + 4];
      *(float4*)&xHI[0] = *(const float4*)&yHI[base];
      *(float4*)&xHI[4] = *(const float4*)&yHI[base + 4];
      float o[8][2];
#pragma unroll
      for (int u = 0; u < 2; ++u) {
        band6(&xLR[2 * u], &xLI[2 * u], o[0][u], o[1][u], o[2][u], o[3][u]);
        band6(&xHR[2 * u], &xHI[2 * u], o[4][u], o[5][u], o[6][u], o[7][u]);
      }
      const int gi = i0 + p * HB + il;
      const int gj = j0g + 2 * jq;
      const int rlo = gi, rhi = h2 + gi, clo = gj, chi = w2 + gj;
      auto st = [&](float* pdst, int v) {
        f2v t;
        t.x = o[v][0];
        t.y = o[v][1];
        __builtin_nontemporal_store(t, (f2v*)pdst);
      };
      st(outR + (size_t)rlo * W0 + chi, 2);  // LH
      st(outI + (size_t)rlo * W0 + chi, 3);
      st(outR + (size_t)rhi * W0 + clo, 4);  // HL
      st(outI + (size_t)rhi * W0 + clo, 5);
      st(outR + (size_t)rhi * W0 + chi, 6);  // HH
      st(outI + (size_t)rhi * W0 + chi, 7);
      if (LL_TO_WS) {
        const size_t off = (size_t)plane * h2 * w2 + (size_t)gi * w2 + gj;
        f2v a, b;
        a.x = o[0][0];
        a.y = o[0][1];
        b.x = o[1][0];
        b.y = o[1][1];
        *(f2v*)(llR + off) = a;  // cached: next level reads these
        *(f2v*)(llI + off) = b;
      } else {
        st(outR + (size_t)rlo * W0 + clo, 0);  // LL
        st(outI + (size_t)rlo * W0 + clo, 1);
      }
    }
    __syncthreads();
  }
}

// ------------------- fused tail: levels 3,4,5, 1 block/plane ---------------
__global__ __launch_bounds__(256) void dwt_tail_kernel(
    const float* __restrict__ ws0R, const float* __restrict__ ws0I,
    float* __restrict__ out, float* __restrict__ tmpAR,
    float* __restrict__ tmpAI, float* __restrict__ tmpBR,
    float* __restrict__ tmpBI, int HW, int W0) {
  __shared__ float4 s4R[1280], s4I[1280];
  __shared__ __align__(16) float yLR[16 * 72], yLI[16 * 72];
  __shared__ __align__(16) float yHR[16 * 72], yHI[16 * 72];

  const int tid = threadIdx.x;
  const int plane = blockIdx.x;
  float* outR = out + (size_t)plane * 2 * HW;
  float* outI = outR + HW;

  for (int lvl = 0; lvl < 3; ++lvl) {
    const int h = 128 >> lvl;             // 128, 64, 32
    const int TB = (lvl == 2) ? 16 : 32;  // band tile side
    const int tpr = (h / 2) / TB;         // 2, 1, 1
    const int ntiles = tpr * tpr;
    const int HB = TB / 2;
    const int F4PR = TB / 2 + 2;
    const int SW = 4 * F4PR;
    const int NF4 = (2 * TB + 4) * F4PR;
    const int NF4P = ((NF4 + 255) / 256) * 256;
    const int YW = 2 * TB + 8;
    const int C2 = 2 * TB + 4;
    const int hm = h - 1, w4 = h >> 2, w4m = w4 - 1;
    const int h2 = h >> 1;
    const bool llToOut = (lvl == 2);

    const float* pinR;
    const float* pinI;
    float* plR = nullptr;
    float* plI = nullptr;
    if (lvl == 0) {
      pinR = ws0R + (size_t)plane * 128 * 128;
      pinI = ws0I + (size_t)plane * 128 * 128;
      plR = tmpAR + (size_t)plane * 64 * 64;
      plI = tmpAI + (size_t)plane * 64 * 64;
    } else if (lvl == 1) {
      pinR = tmpAR + (size_t)plane * 64 * 64;
      pinI = tmpAI + (size_t)plane * 64 * 64;
      plR = tmpBR + (size_t)plane * 32 * 32;
      plI = tmpBI + (size_t)plane * 32 * 32;
    } else {
      pinR = tmpBR + (size_t)plane * 32 * 32;
      pinI = tmpBI + (size_t)plane * 32 * 32;
    }

    for (int t = 0; t < ntiles; ++t) {
      const int ti = t / tpr;
      const int tj = t - ti * tpr;
      const int rowstart = 2 * TB * ti - 3;
      const int col4start = HB * tj - 1;

      {  // stage 1
        const int lane = tid & 63;
        const int wid = tid >> 6;
        for (int c0 = wid * 64; c0 < NF4P; c0 += 256) {
          const int idx = c0 + lane;
          const int r = idx / F4PR;
          const int q = idx - r * F4PR;
          const int gr = (rowstart + r) & hm;
          const int gq = (col4start + q) & w4m;
          const size_t goff = (size_t)gr * w4 + gq;
          gload16((const float4*)pinR + goff, &s4R[c0]);
          gload16((const float4*)pinI + goff, &s4I[c0]);
        }
      }
      __syncthreads();

      const float* sRf = (const float*)s4R;
      const float* sIf = (const float*)s4I;
      const int i0 = TB * ti, j0g = TB * tj;

      for (int p = 0; p < 2; ++p) {
        for (int idx = tid; idx < HB * C2; idx += 256) {
          const int il = idx / C2;
          const int c = idx - il * C2;
          const int rb = 2 * (p * HB + il);
          const float* col = sRf + rb * SW + c + 1;
          const float* colI = sIf + rb * SW + c + 1;
          const float x0 = col[0], x1 = col[SW], x2 = col[2 * SW];
          const float x3 = col[3 * SW], x4 = col[4 * SW], x5 = col[5 * SW];
          const float z0 = colI[0], z1 = colI[SW], z2 = colI[2 * SW];
          const float z3 = colI[3 * SW], z4 = colI[4 * SW], z5 = colI[5 * SW];
          const float sr0 = x0 + x5, sr1 = x1 + x4, sr2 = x2 + x3;
          const float dr0 = x0 - x5, dr1 = x1 - x4, dr2 = x2 - x3;
          const float si0 = z0 + z5, si1 = z1 + z4, si2 = z2 + z3;
          const float di0 = z0 - z5, di1 = z1 - z4, di2 = z2 - z3;
          const float lr = kLOR0 * sr0 + kLOR1 * sr1 + kLOR2 * sr2 -
                           (kLOI0 * si0 + kLOI1 * si1 + kLOI2 * si2);
          const float li = kLOI0 * sr0 + kLOI1 * sr1 + kLOI2 * sr2 +
                           (kLOR0 * si0 + kLOR1 * si1 + kLOR2 * si2);
          const float hr = kHIR0 * dr0 + kHIR1 * dr1 + kHIR2 * dr2 -
                           (kHII0 * di0 + kHII1 * di1 + kHII2 * di2);
          const float hi = kHII0 * dr0 + kHII1 * dr1 + kHII2 * dr2 +
                           (kHIR0 * di0 + kHIR1 * di1 + kHIR2 * di2);
          const int yi = il * YW + c;
          yLR[yi] = lr;
          yLI[yi] = li;
          yHR[yi] = hr;
          yHI[yi] = hi;
        }
        __syncthreads();

        const int NJQ = TB / 2;
        const int jq = tid & (NJQ - 1);
        const int il = tid / NJQ;
        if (il < HB) {
          const int base = il * YW + 4 * jq;
          float xLR[8], xLI[8], xHR[8], xHI[8];
          *(float4*)&xLR[0] = *(const float4*)&yLR[base];
          *(float4*)&xLR[4] = *(const float4*)&yLR[base + 4];
          *(float4*)&xLI[0] = *(const float4*)&yLI[base];
          *(float4*)&xLI[4] = *(const float4*)&yLI[base + 4];
          *(float4*)&xHR[0] = *(const float4*)&yHR[base];
          *(float4*)&xHR[4] = *(const float4*)&yHR[base + 4];
          *(float4*)&xHI[0] = *(const float4*)&yHI[base];
          *(float4*)&xHI[4] = *(const float4*)&yHI[base + 4];
          float o[8][2];
#pragma unroll
          for (int u = 0; u < 2; ++u) {
            band6(&xLR[2 * u], &xLI[2 * u], o[0][u], o[1][u], o[2][u],
                  o[3][u]);
            band6(&xHR[2 * u], &xHI[2 * u], o[4][u], o[5][u], o[6][u],
                  o[7][u]);
          }
          const int gi = i0 + p * HB + il;
          const int gj = j0g + 2 * jq;
          const int rlo = gi, rhi = h2 + gi, clo = gj, chi = h2 + gj;
          auto st = [&](float* pdst, int v) {
            f2v tv;
            tv.x = o[v][0];
            tv.y = o[v][1];
            __builtin_nontemporal_store(tv, (f2v*)pdst);
          };
          st(outR + (size_t)rlo * W0 + chi, 2);
          st(outI + (size_t)rlo * W0 + chi, 3);
          st(outR + (size_t)rhi * W0 + clo, 4);
          st(outI + (size_t)rhi * W0 + clo, 5);
          st(outR + (size_t)rhi * W0 + chi, 6);
          st(outI + (size_t)rhi * W0 + chi, 7);
          if (llToOut) {
            st(outR + (size_t)rlo * W0 + clo, 0);
            st(outI + (size_t)rlo * W0 + clo, 1);
          } else {
            const size_t off = (size_t)gi * h2 + gj;
            f2v a, b;
            a.x = o[0][0];
            a.y = o[0][1];
            b.x = o[1][0];
            b.y = o[1][1];
            *(f2v*)(plR + off) = a;
            *(f2v*)(plI + off) = b;
          }
        }
        __syncthreads();
      }
    }
    // global writes by this block are drained by the waitcnt in the final
    // __syncthreads above; next level reads its own plane only.
  }
}

extern "C" void kernel_launch(void* const* d_in, const int* in_sizes, int n_in,
                              void* d_out, int out_size, void* d_ws,
                              size_t ws_size, hipStream_t stream) {
  const float* images = (const float*)d_in[0];
  float* out = (float*)d_out;
  constexpr int B = 8, C = 3, H = 1024, W = 1024;
  constexpr int NP = B * C;

  float* wsf = (float*)d_ws;
  const size_t S0 = (size_t)NP * 512 * 512;
  const size_t S1 = (size_t)NP * 256 * 256;
  float* buf0R = wsf;
  float* buf0I = wsf + S0;
  float* buf1R = wsf + 2 * S0;
  float* buf1I = wsf + 2 * S0 + S1;
  // tail tmp buffers live in buf1 space (free once level 2 has read it? no:
  // level 2 reads buf1 (level-1 LL), writes buf0. Tail reads buf0. So buf1 is
  // dead during the tail -> reuse for tmpA/tmpB.
  float* tmpAR = buf1R;                          // NP*64*64
  float* tmpAI = buf1I;
  float* tmpBR = buf1R + (size_t)NP * 64 * 64;   // NP*32*32
  float* tmpBI = buf1I + (size_t)NP * 64 * 64;

  // level 0: 1024 -> bands 512, TB=32 -> 16x16 tiles/plane
  {
    const int tpr = 512 / 32, tpp = tpr * tpr, grid = NP * tpp;
    dwt_kernel<32, false, true><<<grid, 256, 0, stream>>>(
        images, nullptr, out, buf0R, buf0I, 1024, 1024, tpr, tpp, grid / 8,
        H * W, W);
  }
  // level 1: 512 -> bands 256
  {
    const int tpr = 256 / 32, tpp = tpr * tpr, grid = NP * tpp;
    dwt_kernel<32, true, true><<<grid, 256, 0, stream>>>(
        buf0R, buf0I, out, buf1R, buf1I, 512, 512, tpr, tpp, grid / 8, H * W,
        W);
  }
  // level 2: 256 -> bands 128 (LL -> buf0, read by tail)
  {
    const int tpr = 128 / 32, tpp = tpr * tpr, grid = NP * tpp;
    dwt_kernel<32, true, true><<<grid, 256, 0, stream>>>(
        buf1R, buf1I, out, buf0R, buf0I, 256, 256, tpr, tpp, grid / 8, H * W,
        W);
  }
  // levels 3-5 fused: one block per plane
  dwt_tail_kernel<<<NP, 256, 0, stream>>>(buf0R, buf0I, out, tmpAR, tmpAI,
                                          tmpBR, tmpBI, H * W, W);
}

// Round 5
// 98.376 us; speedup vs baseline: 1.1156x; 1.1156x over previous
//
#include <hip/hip_runtime.h>

// ---------------------------------------------------------------------------
// Complex Daubechies wavelet pyramid, 6 levels, circular boundary, 6 taps.
// d_out = [B, C, 2, H, W] fp32. One tiled dispatch per level (fused column
// pass -> row pass). LL band of levels 0..4 goes ONLY to ws (it would be
// overwritten in d_out by the next level); level 5 writes LL to d_out.
// Filters: LO palindromic, HI antipalindromic -> fold 6 taps to 3.
// Stage 2 writes y with stride YW = 2TB+8 so stage 3 reads its 12-float tap
// window as 3x ds_read_b128 per array; stage 3 = 4 output cols per thread,
// 16B nontemporal stores (clang ext_vector_type -- HIP float4 is rejected by
// __builtin_nontemporal_store).
// ---------------------------------------------------------------------------

#define SQ2 0.7071067811865476

constexpr float kLOR0 = (float)(-0.0662912607 * SQ2);
constexpr float kLOR1 = (float)( 0.1104854346 * SQ2);
constexpr float kLOR2 = (float)( 0.6629126074 * SQ2);
constexpr float kLOI0 = (float)(-0.0855816496 * SQ2);
constexpr float kLOI1 = (float)(-0.0855816496 * SQ2);
constexpr float kLOI2 = (float)( 0.1711632992 * SQ2);
constexpr float kHIR0 = (float)(-0.0662912607 * SQ2);
constexpr float kHIR1 = (float)(-0.1104854346 * SQ2);
constexpr float kHIR2 = (float)( 0.6629126074 * SQ2);
constexpr float kHII0 = (float)( 0.0855816496 * SQ2);
constexpr float kHII1 = (float)(-0.0855816496 * SQ2);
constexpr float kHII2 = (float)(-0.1711632992 * SQ2);

typedef float f4v __attribute__((ext_vector_type(4)));

// 6-tap complex filter pair via (anti)symmetry. xr/xi: 6 consecutive values
// (register arrays, statically indexed after unroll).
__device__ __forceinline__ void band6(const float* xr, const float* xi,
                                      float& plr, float& pli, float& phr,
                                      float& phi) {
  const float s0 = xr[0] + xr[5], s1 = xr[1] + xr[4], s2 = xr[2] + xr[3];
  const float d0 = xr[0] - xr[5], d1 = xr[1] - xr[4], d2 = xr[2] - xr[3];
  const float t0 = xi[0] + xi[5], t1 = xi[1] + xi[4], t2 = xi[2] + xi[3];
  const float e0 = xi[0] - xi[5], e1 = xi[1] - xi[4], e2 = xi[2] - xi[3];
  plr = (kLOR0 * s0 + kLOR1 * s1 + kLOR2 * s2) -
        (kLOI0 * t0 + kLOI1 * t1 + kLOI2 * t2);
  pli = (kLOI0 * s0 + kLOI1 * s1 + kLOI2 * s2) +
        (kLOR0 * t0 + kLOR1 * t1 + kLOR2 * t2);
  phr = (kHIR0 * d0 + kHIR1 * d1 + kHIR2 * d2) -
        (kHII0 * e0 + kHII1 * e1 + kHII2 * e2);
  phi = (kHII0 * d0 + kHII1 * d1 + kHII2 * d2) +
        (kHIR0 * e0 + kHIR1 * e1 + kHIR2 * e2);
}

__device__ __forceinline__ void gload16(const f4v* src, f4v* ldsDst) {
  __builtin_amdgcn_global_load_lds(
      (__attribute__((address_space(1))) const void*)src,
      (__attribute__((address_space(3))) void*)ldsDst, 16, 0, 0);
}

// ---------------------------- tiled level kernel ---------------------------
template <int TB, bool HAS_IMAG, bool LL_TO_WS>
__global__ __launch_bounds__(256) void dwt_kernel(
    const float* __restrict__ inR, const float* __restrict__ inI,
    float* __restrict__ out, float* __restrict__ llR, float* __restrict__ llI,
    int h, int w, int tilesPerRow, int tilesPerPlane, int cpx8, int HW,
    int W0) {
  constexpr int RROWS = 2 * TB + 4;
  constexpr int F4PR = TB / 2 + 2;
  constexpr int SW = 4 * F4PR;
  constexpr int NF4 = RROWS * F4PR;
  constexpr int NF4P = ((NF4 + 255) / 256) * 256;
  constexpr int YW = 2 * TB + 8;   // mult of 4 -> 16B-aligned windows
  constexpr int C2 = 2 * TB + 4;   // stage-2 outputs per row
  constexpr int HB = TB / 2;
  constexpr int NJQ4 = TB / 4;     // stage-3 col groups (4 cols each)

  __shared__ f4v s4R[NF4P];
  __shared__ f4v s4I[HAS_IMAG ? NF4P : 1];
  __shared__ __align__(16) float yLR[HB * YW], yLI[HB * YW];
  __shared__ __align__(16) float yHR[HB * YW], yHI[HB * YW];

  const int tid = threadIdx.x;
  int bid = (int)blockIdx.x;
  bid = (bid & 7) * cpx8 + (bid >> 3);  // XCD-contiguous chunks
  const int plane = bid / tilesPerPlane;
  const int trem = bid - plane * tilesPerPlane;
  const int ti = trem / tilesPerRow;
  const int tj = trem - ti * tilesPerRow;

  const int hm = h - 1;
  const int w4 = w >> 2, w4m = w4 - 1;
  const int rowstart = 2 * TB * ti - 3;
  const int col4start = HB * tj - 1;

  const float* pinR = inR + (size_t)plane * h * w;
  const float* pinI = HAS_IMAG ? (inI + (size_t)plane * h * w) : nullptr;

  // ---- stage 1: global -> LDS, width-16 async, linear LDS layout ----
  {
    const int lane = tid & 63;
    const int wid = tid >> 6;
    for (int c0 = wid * 64; c0 < NF4P; c0 += 256) {
      const int idx = c0 + lane;
      const int r = idx / F4PR;
      const int q = idx - r * F4PR;
      const int gr = (rowstart + r) & hm;
      const int gq = (col4start + q) & w4m;
      const size_t goff = (size_t)gr * w4 + gq;
      gload16((const f4v*)pinR + goff, &s4R[c0]);
      if (HAS_IMAG) gload16((const f4v*)pinI + goff, &s4I[c0]);
    }
  }
  __syncthreads();

  const float* sRf = (const float*)s4R;
  const float* sIf = (const float*)s4I;
  const int i0 = TB * ti, j0g = TB * tj;
  const int h2 = h >> 1, w2 = w >> 1;
  float* outR = out + (size_t)plane * 2 * HW;
  float* outI = outR + HW;

#pragma unroll
  for (int p = 0; p < 2; ++p) {
    // ---- stage 2: column pass; y[c] ~ padded input col (c+1) ----
    for (int idx = tid; idx < HB * C2; idx += 256) {
      const int il = idx / C2;
      const int c = idx - il * C2;
      const int rb = 2 * (p * HB + il);
      const float* col = sRf + rb * SW + c + 1;
      const float x0 = col[0], x1 = col[SW], x2 = col[2 * SW];
      const float x3 = col[3 * SW], x4 = col[4 * SW], x5 = col[5 * SW];
      const float sr0 = x0 + x5, sr1 = x1 + x4, sr2 = x2 + x3;
      const float dr0 = x0 - x5, dr1 = x1 - x4, dr2 = x2 - x3;
      float lr = kLOR0 * sr0 + kLOR1 * sr1 + kLOR2 * sr2;
      float li = kLOI0 * sr0 + kLOI1 * sr1 + kLOI2 * sr2;
      float hr = kHIR0 * dr0 + kHIR1 * dr1 + kHIR2 * dr2;
      float hi = kHII0 * dr0 + kHII1 * dr1 + kHII2 * dr2;
      if (HAS_IMAG) {
        const float* colI = sIf + rb * SW + c + 1;
        const float z0 = colI[0], z1 = colI[SW], z2 = colI[2 * SW];
        const float z3 = colI[3 * SW], z4 = colI[4 * SW], z5 = colI[5 * SW];
        const float si0 = z0 + z5, si1 = z1 + z4, si2 = z2 + z3;
        const float di0 = z0 - z5, di1 = z1 - z4, di2 = z2 - z3;
        lr -= kLOI0 * si0 + kLOI1 * si1 + kLOI2 * si2;
        li += kLOR0 * si0 + kLOR1 * si1 + kLOR2 * si2;
        hr -= kHII0 * di0 + kHII1 * di1 + kHII2 * di2;
        hi += kHIR0 * di0 + kHIR1 * di1 + kHIR2 * di2;
      }
      const int yi = il * YW + c;
      yLR[yi] = lr;
      yLI[yi] = li;
      yHR[yi] = hr;
      yHI[yi] = hi;
    }
    __syncthreads();

    // ---- stage 3: row pass, 4 cols/thread, 3x b128 window reads/array ----
    const int jq = tid & (NJQ4 - 1);
    const int il = tid / NJQ4;
    if (il < HB) {
      const int base = il * YW + 8 * jq;  // y[8jq .. 8jq+11]
      float xLR[12], xLI[12], xHR[12], xHI[12];
      *(f4v*)&xLR[0] = *(const f4v*)&yLR[base];
      *(f4v*)&xLR[4] = *(const f4v*)&yLR[base + 4];
      *(f4v*)&xLR[8] = *(const f4v*)&yLR[base + 8];
      *(f4v*)&xLI[0] = *(const f4v*)&yLI[base];
      *(f4v*)&xLI[4] = *(const f4v*)&yLI[base + 4];
      *(f4v*)&xLI[8] = *(const f4v*)&yLI[base + 8];
      *(f4v*)&xHR[0] = *(const f4v*)&yHR[base];
      *(f4v*)&xHR[4] = *(const f4v*)&yHR[base + 4];
      *(f4v*)&xHR[8] = *(const f4v*)&yHR[base + 8];
      *(f4v*)&xHI[0] = *(const f4v*)&yHI[base];
      *(f4v*)&xHI[4] = *(const f4v*)&yHI[base + 4];
      *(f4v*)&xHI[8] = *(const f4v*)&yHI[base + 8];
      float o[8][4];
#pragma unroll
      for (int u = 0; u < 4; ++u) {
        band6(&xLR[2 * u], &xLI[2 * u], o[0][u], o[1][u], o[2][u], o[3][u]);
        band6(&xHR[2 * u], &xHI[2 * u], o[4][u], o[5][u], o[6][u], o[7][u]);
      }
      const int gi = i0 + p * HB + il;
      const int gj = j0g + 4 * jq;
      const int rlo = gi, rhi = h2 + gi, clo = gj, chi = w2 + gj;
      auto st = [&](float* pdst, int v) {
        f4v t;
        t.x = o[v][0];
        t.y = o[v][1];
        t.z = o[v][2];
        t.w = o[v][3];
        __builtin_nontemporal_store(t, (f4v*)pdst);
      };
      st(outR + (size_t)rlo * W0 + chi, 2);  // LH
      st(outI + (size_t)rlo * W0 + chi, 3);
      st(outR + (size_t)rhi * W0 + clo, 4);  // HL
      st(outI + (size_t)rhi * W0 + clo, 5);
      st(outR + (size_t)rhi * W0 + chi, 6);  // HH
      st(outI + (size_t)rhi * W0 + chi, 7);
      if (LL_TO_WS) {
        const size_t off = (size_t)plane * h2 * w2 + (size_t)gi * w2 + gj;
        f4v a, b;
        a.x = o[0][0];
        a.y = o[0][1];
        a.z = o[0][2];
        a.w = o[0][3];
        b.x = o[1][0];
        b.y = o[1][1];
        b.z = o[1][2];
        b.w = o[1][3];
        *(f4v*)(llR + off) = a;  // cached: next level reads these
        *(f4v*)(llI + off) = b;
      } else {
        st(outR + (size_t)rlo * W0 + clo, 0);  // LL (final level)
        st(outI + (size_t)rlo * W0 + clo, 1);
      }
    }
    __syncthreads();
  }
}

extern "C" void kernel_launch(void* const* d_in, const int* in_sizes, int n_in,
                              void* d_out, int out_size, void* d_ws,
                              size_t ws_size, hipStream_t stream) {
  const float* images = (const float*)d_in[0];
  float* out = (float*)d_out;
  constexpr int B = 8, C = 3, H = 1024, W = 1024;
  constexpr int NP = B * C;

  float* wsf = (float*)d_ws;
  const size_t S0 = (size_t)NP * 512 * 512;
  const size_t S1 = (size_t)NP * 256 * 256;
  float* buf0R = wsf;
  float* buf0I = wsf + S0;
  float* buf1R = wsf + 2 * S0;
  float* buf1I = wsf + 2 * S0 + S1;

  // Alternation: L0 w->buf0, L1 r buf0 w buf1, L2 r buf1 w buf0,
  // L3 r buf0 w buf1, L4 r buf1 w buf0, L5 r buf0 w out. Sizes shrink, so
  // smaller levels reuse the big buffers' space.
  auto launch = [&](auto tb_tag, bool hasImag, bool llToWs, const float* iR,
                    const float* iI, float* lR, float* lI, int hsz) {
    constexpr int TB = decltype(tb_tag)::value;
    const int tpr = (hsz / 2) / TB;
    const int tpp = tpr * tpr;
    const int grid = NP * tpp;
    if (!hasImag) {
      dwt_kernel<TB, false, true><<<grid, 256, 0, stream>>>(
          iR, nullptr, out, lR, lI, hsz, hsz, tpr, tpp, grid / 8, H * W, W);
    } else if (llToWs) {
      dwt_kernel<TB, true, true><<<grid, 256, 0, stream>>>(
          iR, iI, out, lR, lI, hsz, hsz, tpr, tpp, grid / 8, H * W, W);
    } else {
      dwt_kernel<TB, true, false><<<grid, 256, 0, stream>>>(
          iR, iI, out, nullptr, nullptr, hsz, hsz, tpr, tpp, grid / 8, H * W,
          W);
    }
  };

  launch(std::integral_constant<int, 32>{}, false, true, images, nullptr,
         buf0R, buf0I, 1024);                                   // L0
  launch(std::integral_constant<int, 32>{}, true, true, buf0R, buf0I, buf1R,
         buf1I, 512);                                           // L1
  launch(std::integral_constant<int, 32>{}, true, true, buf1R, buf1I, buf0R,
         buf0I, 256);                                           // L2
  launch(std::integral_constant<int, 32>{}, true, true, buf0R, buf0I, buf1R,
         buf1I, 128);                                           // L3
  launch(std::integral_constant<int, 16>{}, true, true, buf1R, buf1I, buf0R,
         buf0I, 64);                                            // L4
  launch(std::integral_constant<int, 16>{}, true, false, buf0R, buf0I,
         nullptr, nullptr, 32);                                 // L5
}